// Round 1
// baseline (299.650 us; speedup 1.0000x reference)
//
#include <hip/hip_runtime.h>
#include <math.h>

// Problem constants (B=4, C=128, H=W=64 -> HW=4096), TAU=0.1 -> scale 10.
#define BB 4
#define CC 128
#define HW 4096

// K1: inverse L2 norms over C for every (b, pos) of feat_A and feat_B.
// Also zero-init expsum and the two scalar accumulators (ws is poisoned 0xAA).
__global__ void k_prep(const float* __restrict__ fA, const float* __restrict__ fB,
                       float* __restrict__ invA, float* __restrict__ invB,
                       float* __restrict__ expsum, float* __restrict__ acc) {
  int idx = blockIdx.x * blockDim.x + threadIdx.x;   // 0..32767
  if (idx == 0) { acc[0] = 0.f; acc[1] = 0.f; }
  int pos = idx & 16383;                             // 0..16383 = b*4096+n
  const float* src; float* dst;
  if (idx < 16384) { src = fA; dst = invA; expsum[pos] = 0.f; }
  else             { src = fB; dst = invB; }
  int b = pos >> 12, n = pos & 4095;
  const float* p = src + (size_t)b * CC * HW + n;
  float ss = 0.f;
  #pragma unroll 8
  for (int c = 0; c < CC; ++c) { float v = p[(size_t)c * HW]; ss = fmaf(v, v, ss); }
  dst[pos] = 1.f / fmaxf(sqrtf(ss), 1e-12f);
}

// K2: fused GEMM + exp + column-sum.
// Block handles 64 columns (m) x 2048 rows (n half-range), K=128 staged in
// 32-wide LDS slices. Thread tile 8m x 8n. Per-column sum of exp(sim-10)
// atomically accumulated into expsum (2 partials per column).
__global__ __launch_bounds__(256) void k_main(const float* __restrict__ fA,
                                              const float* __restrict__ fB,
                                              const float* __restrict__ invA,
                                              const float* __restrict__ invB,
                                              float* __restrict__ expsum) {
  __shared__ float sB[CC * 64];    // [k][m]  32 KB, resident all K
  __shared__ float sA[32 * 256];   // [k-slice][n]  32 KB (reused as reduce buf)
  const int tid = threadIdx.x;
  const int bid = blockIdx.x;              // 0..511
  const int b    = bid >> 7;               // 0..3
  const int rem  = bid & 127;
  const int m0   = (rem >> 1) * 64;        // column tile base
  const int nbase = (rem & 1) * 2048;      // n half-range

  const float* fAb = fA + (size_t)b * CC * HW;
  const float* fBb = fB + (size_t)b * CC * HW;

  // Stage B tile: sB[c][m] = feat_B[b][c][m0+m] * invB[m] * 10  (fold /tau)
  {
    int m4 = (tid & 15) * 4;
    int c0 = tid >> 4;                      // 0..15
    float4 ib = *(const float4*)(invB + b * HW + m0 + m4);
    ib.x *= 10.f; ib.y *= 10.f; ib.z *= 10.f; ib.w *= 10.f;
    #pragma unroll
    for (int p = 0; p < 8; ++p) {
      int c = p * 16 + c0;
      float4 v = *(const float4*)(fBb + (size_t)c * HW + m0 + m4);
      v.x *= ib.x; v.y *= ib.y; v.z *= ib.z; v.w *= ib.w;
      *(float4*)(&sB[c * 64 + m4]) = v;
    }
  }

  const int mt = tid >> 5;   // 0..7  (thread's m-group: columns m0+mt*8..+7)
  const int nt = tid & 31;   // 0..31 (thread's n-group within 256-n step)
  const int n4   = (tid & 63) * 4;  // staging: n offset
  const int crow = tid >> 6;        // staging: 0..3

  float colp[8];
  #pragma unroll
  for (int i = 0; i < 8; ++i) colp[i] = 0.f;

  for (int s = 0; s < 8; ++s) {            // 8 n-steps of 256
    const int ns = nbase + s * 256;
    float accr[8][8];
    #pragma unroll
    for (int i = 0; i < 8; ++i)
      #pragma unroll
      for (int j = 0; j < 8; ++j) accr[i][j] = 0.f;

    float4 ia = *(const float4*)(invA + b * HW + ns + n4);

    for (int kc = 0; kc < 4; ++kc) {       // K slices of 32
      __syncthreads();
      #pragma unroll
      for (int p = 0; p < 8; ++p) {
        int c = kc * 32 + p * 4 + crow;
        float4 v = *(const float4*)(fAb + (size_t)c * HW + ns + n4);
        v.x *= ia.x; v.y *= ia.y; v.z *= ia.z; v.w *= ia.w;
        *(float4*)(&sA[(p * 4 + crow) * 256 + n4]) = v;
      }
      __syncthreads();
      #pragma unroll 4
      for (int k = 0; k < 32; ++k) {
        float av[8], bv[8];
        #pragma unroll
        for (int j = 0; j < 2; ++j) {
          *(float4*)(&av[j * 4]) = *(const float4*)(&sA[k * 256 + nt * 8 + j * 4]);
          *(float4*)(&bv[j * 4]) = *(const float4*)(&sB[(kc * 32 + k) * 64 + mt * 8 + j * 4]);
        }
        #pragma unroll
        for (int i = 0; i < 8; ++i)
          #pragma unroll
          for (int j = 0; j < 8; ++j)
            accr[i][j] = fmaf(bv[i], av[j], accr[i][j]);
      }
    }
    // epilogue for this n-step: sum exp(sim - 10) per column
    #pragma unroll
    for (int i = 0; i < 8; ++i) {
      float e = 0.f;
      #pragma unroll
      for (int j = 0; j < 8; ++j) e += __expf(accr[i][j] - 10.f);
      colp[i] += e;
    }
  }

  // Block reduction over the 32 n-thread-groups per column (reuse sA).
  __syncthreads();
  #pragma unroll
  for (int i = 0; i < 8; ++i) sA[nt * 64 + mt * 8 + i] = colp[i];
  __syncthreads();
  if (tid < 64) {
    float ssum = 0.f;
    #pragma unroll 8
    for (int r = 0; r < 32; ++r) ssum += sA[r * 64 + tid];
    atomicAdd(&expsum[b * HW + m0 + tid], ssum);
  }
}

// K3: diagonal similarity + per-position loss + masked reduction.
__global__ void k_diag(const float* __restrict__ fA, const float* __restrict__ fB,
                       const float* __restrict__ invA, const float* __restrict__ invB,
                       const float* __restrict__ mask, const float* __restrict__ expsum,
                       float* __restrict__ acc) {
  int idx = blockIdx.x * blockDim.x + threadIdx.x;   // 0..16383
  int b = idx >> 12, k = idx & 4095;
  const float* pa = fA + (size_t)b * CC * HW + k;
  const float* pb = fB + (size_t)b * CC * HW + k;
  float s = 0.f;
  #pragma unroll 8
  for (int c = 0; c < CC; ++c) s = fmaf(pa[(size_t)c * HW], pb[(size_t)c * HW], s);
  float simkk = s * invA[idx] * invB[idx] * 10.f;
  float lse = 10.f + __logf(expsum[idx]);
  float mv = mask[idx];
  float contrib = mv * (lse - simkk);
  // wave64 butterfly reduce, then one atomic per wave
  #pragma unroll
  for (int off = 32; off; off >>= 1) {
    contrib += __shfl_down(contrib, off, 64);
    mv      += __shfl_down(mv, off, 64);
  }
  if ((threadIdx.x & 63) == 0) {
    atomicAdd(&acc[0], contrib);
    atomicAdd(&acc[1], mv);
  }
}

__global__ void k_final(const float* __restrict__ acc, float* __restrict__ out) {
  if (threadIdx.x == 0) out[0] = acc[0] / (acc[1] + 1e-6f);
}

extern "C" void kernel_launch(void* const* d_in, const int* in_sizes, int n_in,
                              void* d_out, int out_size, void* d_ws, size_t ws_size,
                              hipStream_t stream) {
  const float* feat_A = (const float*)d_in[0];
  const float* feat_B = (const float*)d_in[1];
  // d_in[2] = H_mat : unused by the reference computation
  const float* vmask  = (const float*)d_in[3];

  float* ws     = (float*)d_ws;
  float* invA   = ws;               // 16384 floats
  float* invB   = ws + 16384;       // 16384
  float* expsum = ws + 32768;       // 16384
  float* acc    = ws + 49152;       // 2
  float* out    = (float*)d_out;

  k_prep <<<128, 256, 0, stream>>>(feat_A, feat_B, invA, invB, expsum, acc);
  k_main <<<512, 256, 0, stream>>>(feat_A, feat_B, invA, invB, expsum);
  k_diag <<<64, 256, 0, stream>>>(feat_A, feat_B, invA, invB, vmask, expsum, acc);
  k_final<<<1, 64, 0, stream>>>(acc, out);
}

// Round 2
// 106.453 us; speedup vs baseline: 2.8148x; 2.8148x over previous
//
#include <hip/hip_runtime.h>
#include <math.h>

#define BB 4
#define CC 128
#define HW 4096
#define SC10 3.16227766016838f   // sqrt(10) folded into each normalized side

typedef short short8 __attribute__((ext_vector_type(8)));
typedef float f32x4 __attribute__((ext_vector_type(4)));

static __device__ inline unsigned short f2bf(float f) {
  // round-to-nearest-even fp32 -> bf16 (inputs are finite)
  unsigned int u = __float_as_uint(f);
  u += 0x7fffu + ((u >> 16) & 1u);
  return (unsigned short)(u >> 16);
}

// K1: per 32-position tile of one batch: compute inv-norms of A and B, the
// diagonal similarity (fp32), zero expsum, and write bf16 normalized*sqrt(10)
// features transposed to [b][pos][c] with XOR-swizzled 16B chunks within each
// 256B row: global chunk position q holds data chunk q^(n&7). This makes
// k_main's global_load_lds staging an identity copy while its MFMA fragment
// ds_reads become 2-way-conflict (free).
__global__ __launch_bounds__(256) void k_prep(const float* __restrict__ fA,
                                              const float* __restrict__ fB,
                                              unsigned short* __restrict__ fAn,
                                              unsigned short* __restrict__ fBn,
                                              float* __restrict__ diag,
                                              float* __restrict__ expsum) {
  __shared__ float sA[32 * 129];   // [n][c], pad->bank-conflict-free
  __shared__ float sB[32 * 129];
  __shared__ float red[3 * 256];

  const int bid = blockIdx.x;          // 0..511 : b*128 + tile
  const int b   = bid >> 7;
  const int n0  = (bid & 127) * 32;
  const int tid = threadIdx.x;
  const int cR  = tid >> 5;            // 0..7
  const int n   = tid & 31;            // 0..31

  const float* pa = fA + (size_t)b * CC * HW + n0 + n;
  const float* pb = fB + (size_t)b * CC * HW + n0 + n;

  float ssa = 0.f, ssb = 0.f, dot = 0.f;
  #pragma unroll
  for (int it = 0; it < 16; ++it) {
    int c = it * 8 + cR;
    float va = pa[(size_t)c * HW];
    float vb = pb[(size_t)c * HW];
    sA[n * 129 + c] = va;
    sB[n * 129 + c] = vb;
    ssa = fmaf(va, va, ssa);
    ssb = fmaf(vb, vb, ssb);
    dot = fmaf(va, vb, dot);
  }
  red[tid] = ssa; red[256 + tid] = ssb; red[512 + tid] = dot;
  __syncthreads();

  if (tid < 32) {
    float sa = 0.f, sb = 0.f, dt = 0.f;
    #pragma unroll
    for (int k = 0; k < 8; ++k) {
      sa += red[k * 32 + tid];
      sb += red[256 + k * 32 + tid];
      dt += red[512 + k * 32 + tid];
    }
    float ia = 1.f / fmaxf(sqrtf(sa), 1e-12f);
    float ib = 1.f / fmaxf(sqrtf(sb), 1e-12f);
    int gidx = b * HW + n0 + tid;
    diag[gidx]   = dt * ia * ib * 10.f;
    expsum[gidx] = 0.f;
    red[tid]      = ia * SC10;   // safe: thread tid is sole reader/writer of these slots
    red[32 + tid] = ib * SC10;
  }
  __syncthreads();

  // write phase: 32 rows x 16 chunks (16B each) per matrix, 2 rounds
  #pragma unroll
  for (int r = 0; r < 2; ++r) {
    int L  = r * 256 + tid;
    int nn = L >> 4;                  // 0..31
    int q  = L & 15;                  // store position within row
    int c0 = (q ^ (nn & 7)) * 8;      // data chunk (swizzle; n0 is mult of 32)
    size_t base = ((size_t)b * HW + n0 + nn) * 128 + q * 8;
    {
      float sc = red[nn];
      const float* s = &sA[nn * 129 + c0];
      uint4 v;
      v.x = f2bf(s[0]*sc) | ((unsigned)f2bf(s[1]*sc) << 16);
      v.y = f2bf(s[2]*sc) | ((unsigned)f2bf(s[3]*sc) << 16);
      v.z = f2bf(s[4]*sc) | ((unsigned)f2bf(s[5]*sc) << 16);
      v.w = f2bf(s[6]*sc) | ((unsigned)f2bf(s[7]*sc) << 16);
      *(uint4*)(fAn + base) = v;
    }
    {
      float sc = red[32 + nn];
      const float* s = &sB[nn * 129 + c0];
      uint4 v;
      v.x = f2bf(s[0]*sc) | ((unsigned)f2bf(s[1]*sc) << 16);
      v.y = f2bf(s[2]*sc) | ((unsigned)f2bf(s[3]*sc) << 16);
      v.z = f2bf(s[4]*sc) | ((unsigned)f2bf(s[5]*sc) << 16);
      v.w = f2bf(s[6]*sc) | ((unsigned)f2bf(s[7]*sc) << 16);
      *(uint4*)(fBn + base) = v;
    }
  }
}

// K2: 128x128-tile bf16 MFMA GEMM, fused exp(sim-10) + column-sum epilogue.
// sim[n][m] = sum_c An[n][c]*Bn[m][c]  (NT, K=128). Output never materialized.
__global__ __launch_bounds__(256) void k_main(const unsigned short* __restrict__ fAn,
                                              const unsigned short* __restrict__ fBn,
                                              float* __restrict__ expsum) {
  __shared__ unsigned short sAB[2 * 128 * 128];   // 64 KB total; sCol aliases sAB after MFMA
  unsigned short* sA = sAB;
  unsigned short* sB = sAB + 16384;

  const int bid = blockIdx.x;          // 0..4095 : b*1024 + nt*32 + mt
  const int b   = bid >> 10;
  const int tl  = bid & 1023;
  const int n0  = (tl >> 5) * 128;
  const int m0  = (tl & 31) * 128;
  const int tid = threadIdx.x;

  const unsigned short* gA = fAn + ((size_t)b * HW + n0) * 128;
  const unsigned short* gB = fBn + ((size_t)b * HW + m0) * 128;

  // stage both 32 KB tiles: identity copy (global already swizzled)
  #pragma unroll
  for (int r = 0; r < 8; ++r) {
    int L = r * 256 + tid;
    __builtin_amdgcn_global_load_lds(
        (const __attribute__((address_space(1))) unsigned int*)(gA + (size_t)L * 8),
        (__attribute__((address_space(3))) unsigned int*)(sA + L * 8), 16, 0, 0);
    __builtin_amdgcn_global_load_lds(
        (const __attribute__((address_space(1))) unsigned int*)(gB + (size_t)L * 8),
        (__attribute__((address_space(3))) unsigned int*)(sB + L * 8), 16, 0, 0);
  }
  __syncthreads();

  const int wv   = tid >> 6;           // wave 0..3
  const int lane = tid & 63;
  const int wn   = (wv & 1) * 64;      // wave's n-offset in tile
  const int wm   = (wv >> 1) * 64;     // wave's m-offset in tile
  const int ml   = lane & 15;
  const int g    = lane >> 4;          // 0..3

  f32x4 acc[4][4] = {};                // [n_sub][m_sub]

  #pragma unroll
  for (int kc = 0; kc < 4; ++kc) {     // K = 4 x 32
    short8 af[4], bf[4];
    int q = kc * 4 + g;                // data chunk index (8 channels each)
    #pragma unroll
    for (int s = 0; s < 4; ++s) {
      int na = wn + s * 16 + ml;       // na&7 == ml&7
      af[s] = *(const short8*)(sA + na * 128 + ((q ^ (na & 7)) * 8));
      int nb = wm + s * 16 + ml;
      bf[s] = *(const short8*)(sB + nb * 128 + ((q ^ (nb & 7)) * 8));
    }
    #pragma unroll
    for (int i = 0; i < 4; ++i)
      #pragma unroll
      for (int j = 0; j < 4; ++j)
        acc[i][j] = __builtin_amdgcn_mfma_f32_16x16x32_bf16(af[i], bf[j], acc[i][j], 0, 0, 0);
  }

  // epilogue: column sums of exp(sim-10).
  // C/D layout: col(m) = lane&15, row(n) = g*4 + reg  [m89-verified]
  __syncthreads();                     // done with sA/sB; reuse as sCol
  float* sCol = (float*)sAB;           // 256 floats
  #pragma unroll
  for (int j = 0; j < 4; ++j) {
    float e = 0.f;
    #pragma unroll
    for (int i = 0; i < 4; ++i)
      #pragma unroll
      for (int r = 0; r < 4; ++r)
        e += __expf(acc[i][j][r] - 10.f);
    e += __shfl_xor(e, 16, 64);        // reduce across row-groups
    e += __shfl_xor(e, 32, 64);
    if (lane < 16) sCol[wv * 64 + j * 16 + lane] = e;
  }
  __syncthreads();
  if (tid < 128) {
    int m = tid;
    float sum = (m < 64) ? (sCol[m] + sCol[64 + m])
                         : (sCol[128 + (m - 64)] + sCol[192 + (m - 64)]);
    atomicAdd(&expsum[(size_t)b * HW + m0 + m], sum);
  }
}

// K3: single-block masked-mean of (lse - diag); lse = 10 + log(sum exp(sim-10))
__global__ __launch_bounds__(1024) void k_loss(const float* __restrict__ diag,
                                               const float* __restrict__ expsum,
                                               const float* __restrict__ mask,
                                               float* __restrict__ out) {
  __shared__ float rn[1024], rd[1024];
  const int tid = threadIdx.x;
  float num = 0.f, den = 0.f;
  for (int i = tid; i < BB * HW; i += 1024) {
    float lse = 10.f + __logf(expsum[i]);
    float mv  = mask[i];
    num = fmaf(mv, lse - diag[i], num);
    den += mv;
  }
  rn[tid] = num; rd[tid] = den;
  __syncthreads();
  for (int s = 512; s > 0; s >>= 1) {
    if (tid < s) { rn[tid] += rn[tid + s]; rd[tid] += rd[tid + s]; }
    __syncthreads();
  }
  if (tid == 0) out[0] = rn[0] / (rd[0] + 1e-6f);
}

extern "C" void kernel_launch(void* const* d_in, const int* in_sizes, int n_in,
                              void* d_out, int out_size, void* d_ws, size_t ws_size,
                              hipStream_t stream) {
  const float* feat_A = (const float*)d_in[0];
  const float* feat_B = (const float*)d_in[1];
  // d_in[2] = H_mat : unused by the reference computation
  const float* vmask  = (const float*)d_in[3];

  unsigned short* fAn = (unsigned short*)d_ws;                 // 4 MB bf16 [b][n][c] swizzled
  unsigned short* fBn = fAn + (size_t)BB * HW * CC;            // 4 MB
  float* diag   = (float*)(fBn + (size_t)BB * HW * CC);        // 64 KB
  float* expsum = diag + BB * HW;                              // 64 KB
  float* out    = (float*)d_out;

  k_prep<<<512,  256, 0, stream>>>(feat_A, feat_B, fAn, fBn, diag, expsum);
  k_main<<<4096, 256, 0, stream>>>(fAn, fBn, expsum);
  k_loss<<<1,   1024, 0, stream>>>(diag, expsum, vmask, out);
}

// Round 3
// 96.604 us; speedup vs baseline: 3.1018x; 1.1020x over previous
//
#include <hip/hip_runtime.h>
#include <math.h>

#define BB 4
#define CC 128
#define HW 4096
// sqrt(10 * log2(e)) — folds 1/tau AND the exp->exp2 conversion into both
// normalized sides: sim' = sim * log2(e), so exp(sim) == exp2(sim').
#define SCF 3.798282565f

typedef short short8 __attribute__((ext_vector_type(8)));
typedef float f32x4 __attribute__((ext_vector_type(4)));

static __device__ inline unsigned short f2bf(float f) {
  // round-to-nearest-even fp32 -> bf16 (inputs are finite)
  unsigned int u = __float_as_uint(f);
  u += 0x7fffu + ((u >> 16) & 1u);
  return (unsigned short)(u >> 16);
}

static __device__ inline float fast_exp2(float x) {
#if __has_builtin(__builtin_amdgcn_exp2f)
  return __builtin_amdgcn_exp2f(x);
#else
  return exp2f(x);
#endif
}

// K1: per 32-position tile: inv-norms of A and B, fp32 diagonal similarity,
// zero expsum + scalar accumulators, and write bf16 normalized*SCF features
// transposed to [b][pos][c] with XOR-swizzled 16B chunks (position q holds
// data chunk q^(n&7)) so k_main's global_load_lds staging is an identity copy
// while MFMA fragment ds_reads stay 2-way-conflict (free).
__global__ __launch_bounds__(256) void k_prep(const float* __restrict__ fA,
                                              const float* __restrict__ fB,
                                              unsigned short* __restrict__ fAn,
                                              unsigned short* __restrict__ fBn,
                                              float* __restrict__ diag,
                                              float* __restrict__ expsum,
                                              float* __restrict__ acc) {
  __shared__ float sA[32 * 129];
  __shared__ float sB[32 * 129];
  __shared__ float red[3 * 256];

  const int bid = blockIdx.x;          // 0..511 : b*128 + tile
  const int b   = bid >> 7;
  const int n0  = (bid & 127) * 32;
  const int tid = threadIdx.x;
  const int cR  = tid >> 5;            // 0..7
  const int n   = tid & 31;            // 0..31

  if (bid == 0 && tid == 0) { acc[0] = 0.f; acc[1] = 0.f; ((unsigned*)acc)[2] = 0u; }

  const float* pa = fA + (size_t)b * CC * HW + n0 + n;
  const float* pb = fB + (size_t)b * CC * HW + n0 + n;

  float ssa = 0.f, ssb = 0.f, dot = 0.f;
  #pragma unroll
  for (int it = 0; it < 16; ++it) {
    int c = it * 8 + cR;
    float va = pa[(size_t)c * HW];
    float vb = pb[(size_t)c * HW];
    sA[n * 129 + c] = va;
    sB[n * 129 + c] = vb;
    ssa = fmaf(va, va, ssa);
    ssb = fmaf(vb, vb, ssb);
    dot = fmaf(va, vb, dot);
  }
  red[tid] = ssa; red[256 + tid] = ssb; red[512 + tid] = dot;
  __syncthreads();

  if (tid < 32) {
    float sa = 0.f, sb = 0.f, dt = 0.f;
    #pragma unroll
    for (int k = 0; k < 8; ++k) {
      sa += red[k * 32 + tid];
      sb += red[256 + k * 32 + tid];
      dt += red[512 + k * 32 + tid];
    }
    float ia = 1.f / fmaxf(sqrtf(sa), 1e-12f);
    float ib = 1.f / fmaxf(sqrtf(sb), 1e-12f);
    int gidx = b * HW + n0 + tid;
    diag[gidx]   = dt * ia * ib * 10.f;   // true sim scale (1/tau)
    expsum[gidx] = 0.f;
    red[tid]      = ia * SCF;   // sole reader/writer of these slots
    red[32 + tid] = ib * SCF;
  }
  __syncthreads();

  #pragma unroll
  for (int r = 0; r < 2; ++r) {
    int L  = r * 256 + tid;
    int nn = L >> 4;                  // 0..31
    int q  = L & 15;                  // store position within row
    int c0 = (q ^ (nn & 7)) * 8;      // data chunk (swizzle)
    size_t base = ((size_t)b * HW + n0 + nn) * 128 + q * 8;
    {
      float sc = red[nn];
      const float* s = &sA[nn * 129 + c0];
      uint4 v;
      v.x = f2bf(s[0]*sc) | ((unsigned)f2bf(s[1]*sc) << 16);
      v.y = f2bf(s[2]*sc) | ((unsigned)f2bf(s[3]*sc) << 16);
      v.z = f2bf(s[4]*sc) | ((unsigned)f2bf(s[5]*sc) << 16);
      v.w = f2bf(s[6]*sc) | ((unsigned)f2bf(s[7]*sc) << 16);
      *(uint4*)(fAn + base) = v;
    }
    {
      float sc = red[32 + nn];
      const float* s = &sB[nn * 129 + c0];
      uint4 v;
      v.x = f2bf(s[0]*sc) | ((unsigned)f2bf(s[1]*sc) << 16);
      v.y = f2bf(s[2]*sc) | ((unsigned)f2bf(s[3]*sc) << 16);
      v.z = f2bf(s[4]*sc) | ((unsigned)f2bf(s[5]*sc) << 16);
      v.w = f2bf(s[6]*sc) | ((unsigned)f2bf(s[7]*sc) << 16);
      *(uint4*)(fBn + base) = v;
    }
  }
}

// K2: B-resident MFMA GEMM. Block owns (b, n-quarter, 128-column m-tile);
// B-tile stays in LDS, loops 8 A-chunks of 128 rows. Column sums of
// exp2(sim') accumulate in registers across the loop; one atomicAdd per
// column per block at the end. XCD swizzle: blockIdx%8 -> XCD, b = bid&3
// keeps each XCD's working set (~2 MB) inside its 4 MB L2.
__global__ __launch_bounds__(256, 2) void k_main(const unsigned short* __restrict__ fAn,
                                                 const unsigned short* __restrict__ fBn,
                                                 float* __restrict__ expsum) {
  __shared__ unsigned short sB[128 * 128];   // 32 KB, resident all iterations
  __shared__ unsigned short sA[128 * 128];   // 32 KB, per-iteration chunk

  const int bid = blockIdx.x;                // 0..511
  const int x   = bid & 7;                   // XCD
  const int t   = bid >> 3;                  // 0..63
  const int b   = x & 3;
  const int nq  = (x >> 2) | ((t & 1) << 1); // 0..3
  const int mt  = t >> 1;                    // 0..31
  const int m0  = mt * 128;
  const int nbase = nq * 1024;
  const int tid = threadIdx.x;

  const unsigned short* gB = fBn + ((size_t)b * HW + m0) * 128;
  #pragma unroll
  for (int r = 0; r < 8; ++r) {
    int L = r * 256 + tid;
    __builtin_amdgcn_global_load_lds(
        (const __attribute__((address_space(1))) unsigned int*)(gB + (size_t)L * 8),
        (__attribute__((address_space(3))) unsigned int*)(sB + L * 8), 16, 0, 0);
  }

  const int wv   = tid >> 6;
  const int lane = tid & 63;
  const int ml   = lane & 15;
  const int g    = lane >> 4;
  const int wn   = (wv & 1) * 64;    // wave n-offset within chunk
  const int wm   = (wv >> 1) * 64;   // wave m-offset within tile

  float colAcc[4] = {0.f, 0.f, 0.f, 0.f};

  for (int it = 0; it < 8; ++it) {
    __syncthreads();   // prev-iter sA frag reads complete before overwrite
    const unsigned short* gA = fAn + ((size_t)b * HW + nbase + it * 128) * 128;
    #pragma unroll
    for (int r = 0; r < 8; ++r) {
      int L = r * 256 + tid;
      __builtin_amdgcn_global_load_lds(
          (const __attribute__((address_space(1))) unsigned int*)(gA + (size_t)L * 8),
          (__attribute__((address_space(3))) unsigned int*)(sA + L * 8), 16, 0, 0);
    }
    __syncthreads();   // staging complete (barrier drains vmcnt)

    f32x4 acc[4][4] = {};              // [n_sub][m_sub]
    #pragma unroll
    for (int kc = 0; kc < 4; ++kc) {
      short8 af[4], bf[4];
      int q = kc * 4 + g;
      #pragma unroll
      for (int s = 0; s < 4; ++s) {
        int na = wn + s * 16 + ml;
        af[s] = *(const short8*)(sA + na * 128 + ((q ^ (na & 7)) * 8));
        int nb = wm + s * 16 + ml;
        bf[s] = *(const short8*)(sB + nb * 128 + ((q ^ (nb & 7)) * 8));
      }
      #pragma unroll
      for (int i = 0; i < 4; ++i)
        #pragma unroll
        for (int j = 0; j < 4; ++j)
          acc[i][j] = __builtin_amdgcn_mfma_f32_16x16x32_bf16(af[i], bf[j], acc[i][j], 0, 0, 0);
    }
    // epilogue: accumulate exp2(sim') per column (C layout: col=lane&15,
    // row=g*4+reg). No shift needed: |sim'| <= 14.43 -> exp2 in [4.6e-5, 2.2e4].
    #pragma unroll
    for (int j = 0; j < 4; ++j) {
      float e = 0.f;
      #pragma unroll
      for (int i = 0; i < 4; ++i)
        #pragma unroll
        for (int r = 0; r < 4; ++r)
          e += fast_exp2(acc[i][j][r]);
      colAcc[j] += e;
    }
  }

  #pragma unroll
  for (int j = 0; j < 4; ++j) {
    float e = colAcc[j];
    e += __shfl_xor(e, 16, 64);
    e += __shfl_xor(e, 32, 64);
    if (lane < 16)
      atomicAdd(&expsum[(size_t)b * HW + m0 + wm + j * 16 + lane], e);
  }
}

// K3: masked mean of (ln(expsum) - diag); 64 blocks, last block finishes.
__global__ __launch_bounds__(256) void k_loss(const float* __restrict__ diag,
                                              const float* __restrict__ expsum,
                                              const float* __restrict__ mask,
                                              float* __restrict__ acc,
                                              float* __restrict__ out) {
  __shared__ float rn[4], rd[4];
  const int i = blockIdx.x * 256 + threadIdx.x;   // 64*256 = 16384
  float lse = __logf(expsum[i]);                  // ln(sum exp(sim))
  float mv  = mask[i];
  float num = mv * (lse - diag[i]);
  #pragma unroll
  for (int off = 32; off; off >>= 1) {
    num += __shfl_down(num, off, 64);
    mv  += __shfl_down(mv,  off, 64);
  }
  const int lane = threadIdx.x & 63, wv = threadIdx.x >> 6;
  if (lane == 0) { rn[wv] = num; rd[wv] = mv; }
  __syncthreads();
  if (threadIdx.x == 0) {
    float n = rn[0] + rn[1] + rn[2] + rn[3];
    float d = rd[0] + rd[1] + rd[2] + rd[3];
    atomicAdd(&acc[0], n);
    atomicAdd(&acc[1], d);
    __threadfence();
    unsigned prev = atomicAdd((unsigned*)(acc + 2), 1u);
    if (prev == 63u) {   // last block: all partials visible (fence-ordered)
      float fn = atomicAdd(&acc[0], 0.f);
      float fd = atomicAdd(&acc[1], 0.f);
      out[0] = fn / (fd + 1e-6f);
    }
  }
}

extern "C" void kernel_launch(void* const* d_in, const int* in_sizes, int n_in,
                              void* d_out, int out_size, void* d_ws, size_t ws_size,
                              hipStream_t stream) {
  const float* feat_A = (const float*)d_in[0];
  const float* feat_B = (const float*)d_in[1];
  // d_in[2] = H_mat : unused by the reference computation
  const float* vmask  = (const float*)d_in[3];

  unsigned short* fAn = (unsigned short*)d_ws;            // 4 MB bf16 [b][n][c] swizzled
  unsigned short* fBn = fAn + (size_t)BB * HW * CC;       // 4 MB
  float* diag   = (float*)(fBn + (size_t)BB * HW * CC);   // 64 KB
  float* expsum = diag + BB * HW;                         // 64 KB
  float* acc    = expsum + BB * HW;                       // 12 B: num, den, ctr
  float* out    = (float*)d_out;

  k_prep<<<512, 256, 0, stream>>>(feat_A, feat_B, fAn, fBn, diag, expsum, acc);
  k_main<<<512, 256, 0, stream>>>(fAn, fBn, expsum);
  k_loss<<<64,  256, 0, stream>>>(diag, expsum, vmask, acc, out);
}